// Round 1
// 2187.237 us; speedup vs baseline: 7.3778x; 7.3778x over previous
//
#include <hip/hip_runtime.h>

#define N_USERS 200000
#define N_ITEMS 400000
#define N_NODES 600000   // N_USERS + N_ITEMS
#define EMB_DIM 128
#define N_EDGES 3000000

#define D4   (EMB_DIM / 4)        // 32 float4 per row
#define TOT4 (N_NODES * D4)       // 19,200,000 float4
#define NU4  (N_USERS * D4)       //  6,400,000 float4

#define SCAN_CHUNK 4096
#define N_CHUNKS ((N_NODES + SCAN_CHUNK - 1) / SCAN_CHUNK)   // 147

// ---------------------------------------------------------------------------
// init: cur = concat(emb_user, emb_item); acc = cur   (no zero-fill needed:
// the CSR SpMM overwrites its full output)
// ---------------------------------------------------------------------------
__global__ void k_init(const float4* __restrict__ eu, const float4* __restrict__ ei,
                       float4* __restrict__ cur, float4* __restrict__ acc) {
    for (int i = blockIdx.x * blockDim.x + threadIdx.x; i < TOT4;
         i += gridDim.x * blockDim.x) {
        float4 v = (i < NU4) ? eu[i] : ei[i - NU4];
        cur[i] = v;
        acc[i] = v;
    }
}

// ---------------------------------------------------------------------------
// CSR build: zero counts -> histogram -> 3-phase exclusive scan -> bucket fill
// ---------------------------------------------------------------------------
__global__ void k_zero_i32(int* __restrict__ p, int n) {
    for (int i = blockIdx.x * blockDim.x + threadIdx.x; i < n;
         i += gridDim.x * blockDim.x)
        p[i] = 0;
}

__global__ void k_hist(const int* __restrict__ row, int* __restrict__ cnt) {
    for (int e = blockIdx.x * blockDim.x + threadIdx.x; e < N_EDGES;
         e += gridDim.x * blockDim.x)
        atomicAdd(&cnt[row[e]], 1);
}

// per-chunk sums (order within chunk irrelevant here)
__global__ void k_scan_part(const int* __restrict__ cnt, int* __restrict__ partial) {
    __shared__ int s[256];
    const int t = threadIdx.x;
    const int base = blockIdx.x * SCAN_CHUNK + t * 16;
    int sum = 0;
    #pragma unroll
    for (int k = 0; k < 16; ++k) {
        int i = base + k;
        if (i < N_NODES) sum += cnt[i];
    }
    s[t] = sum; __syncthreads();
    for (int off = 128; off > 0; off >>= 1) {
        if (t < off) s[t] += s[t + off];
        __syncthreads();
    }
    if (t == 0) partial[blockIdx.x] = s[0];
}

// serial exclusive scan of 147 chunk sums (trivial) + total into rp[N_NODES]
__global__ void k_scan_top(int* partial, int* rp) {
    if (threadIdx.x == 0 && blockIdx.x == 0) {
        int run = 0;
        for (int i = 0; i < N_CHUNKS; ++i) {
            int v = partial[i];
            partial[i] = run;
            run += v;
        }
        rp[N_NODES] = run;   // == N_EDGES
    }
}

// per-chunk exclusive scan; writes row_ptr and initializes the fill cursor.
// NOTE: cnt_in and cursor alias (same buffer) — each index is read then
// written by exactly one thread, and all reads complete before writes
// (they feed tsum -> block scan). No __restrict__ here on purpose.
__global__ void k_scan_apply(const int* cnt_in, const int* __restrict__ partial,
                             int* __restrict__ rp, int* cursor) {
    __shared__ int s[256];
    const int t = threadIdx.x;
    const int base = blockIdx.x * SCAN_CHUNK + t * 16;
    int c[16];
    int tsum = 0;
    #pragma unroll
    for (int k = 0; k < 16; ++k) {
        int i = base + k;
        c[k] = (i < N_NODES) ? cnt_in[i] : 0;
        tsum += c[k];
    }
    s[t] = tsum; __syncthreads();
    // Hillis-Steele inclusive scan over 256 thread sums
    for (int off = 1; off < 256; off <<= 1) {
        int v = (t >= off) ? s[t - off] : 0;
        __syncthreads();
        s[t] += v;
        __syncthreads();
    }
    int pre = partial[blockIdx.x] + s[t] - tsum;   // exclusive prefix
    #pragma unroll
    for (int k = 0; k < 16; ++k) {
        int i = base + k;
        if (i < N_NODES) { rp[i] = pre; cursor[i] = pre; }
        pre += c[k];
    }
}

// scatter edges into row buckets; pack (col, val) as int2 for one 8B load/edge
__global__ void k_fill(const int* __restrict__ row, const int* __restrict__ col,
                       const float* __restrict__ val, int* cursor,
                       int2* __restrict__ ev) {
    for (int e = blockIdx.x * blockDim.x + threadIdx.x; e < N_EDGES;
         e += gridDim.x * blockDim.x) {
        int r = row[e];
        int p = atomicAdd(&cursor[r], 1);
        ev[p] = make_int2(col[e], __float_as_int(val[e]));
    }
}

// ---------------------------------------------------------------------------
// pull-mode CSR SpMM, fused accumulator update.
// One 32-lane half-wave per row; lane owns dims [lane*4, lane*4+4).
//   y[r] = sum_{e in row r} val[e] * x[col[e]]      (single non-atomic write)
//   acc[r] += y[r]            (final_scale: acc[r] = (acc[r]+y[r])*0.25, skip y)
// ---------------------------------------------------------------------------
__global__ void k_spmm_csr(const int* __restrict__ rp, const int2* __restrict__ ev,
                           const float4* __restrict__ x, float4* __restrict__ y,
                           float4* __restrict__ acc, int final_scale) {
    const int lane  = threadIdx.x & 31;
    const int rslot = threadIdx.x >> 5;
    const int rpb   = blockDim.x >> 5;   // rows per block = 8
    for (int r = blockIdx.x * rpb + rslot; r < N_NODES; r += gridDim.x * rpb) {
        const int beg = rp[r], end = rp[r + 1];
        float4 a = make_float4(0.f, 0.f, 0.f, 0.f);
        for (int i = beg; i < end; ++i) {
            const int2  e = ev[i];                 // broadcast across half-wave
            const float v = __int_as_float(e.y);
            const float4 xv = x[(size_t)e.x * D4 + lane];
            a.x += v * xv.x; a.y += v * xv.y; a.z += v * xv.z; a.w += v * xv.w;
        }
        const size_t o = (size_t)r * D4 + lane;
        float4 ac = acc[o];
        ac.x += a.x; ac.y += a.y; ac.z += a.z; ac.w += a.w;
        if (final_scale) {
            ac.x *= 0.25f; ac.y *= 0.25f; ac.z *= 0.25f; ac.w *= 0.25f;
        } else {
            y[o] = a;
        }
        acc[o] = ac;
    }
}

// ---------------------------------------------------------------------------
// Fallback path (previous session's proven kernels) if ws_size is too small
// for the CSR arrays.
// ---------------------------------------------------------------------------
__global__ void k_init_old(const float4* __restrict__ eu, const float4* __restrict__ ei,
                           float4* __restrict__ cur, float4* __restrict__ acc,
                           float4* __restrict__ nxt) {
    for (int i = blockIdx.x * blockDim.x + threadIdx.x; i < TOT4;
         i += gridDim.x * blockDim.x) {
        float4 v = (i < NU4) ? eu[i] : ei[i - NU4];
        cur[i] = v;
        acc[i] = v;
        nxt[i] = make_float4(0.f, 0.f, 0.f, 0.f);
    }
}

__global__ void k_spmm_atomic(const int* __restrict__ row, const int* __restrict__ col,
                              const float* __restrict__ val, const float4* __restrict__ x,
                              float* __restrict__ y) {
    const int lane  = threadIdx.x & 31;
    const int eslot = threadIdx.x >> 5;
    const int epb   = blockDim.x >> 5;
    for (int e = blockIdx.x * epb + eslot; e < N_EDGES; e += gridDim.x * epb) {
        const int   r = row[e];
        const int   c = col[e];
        const float v = val[e];
        float4 xv = x[c * D4 + lane];
        float* yp = y + (size_t)r * EMB_DIM + lane * 4;
        atomicAdd(yp + 0, v * xv.x);
        atomicAdd(yp + 1, v * xv.y);
        atomicAdd(yp + 2, v * xv.z);
        atomicAdd(yp + 3, v * xv.w);
    }
}

__global__ void k_add_zero(float4* __restrict__ acc, const float4* __restrict__ nxt,
                           float4* __restrict__ zbuf) {
    for (int i = blockIdx.x * blockDim.x + threadIdx.x; i < TOT4;
         i += gridDim.x * blockDim.x) {
        float4 a = acc[i], b = nxt[i];
        a.x += b.x; a.y += b.y; a.z += b.z; a.w += b.w;
        acc[i] = a;
        zbuf[i] = make_float4(0.f, 0.f, 0.f, 0.f);
    }
}

__global__ void k_add_scale(float4* __restrict__ acc, const float4* __restrict__ nxt) {
    for (int i = blockIdx.x * blockDim.x + threadIdx.x; i < TOT4;
         i += gridDim.x * blockDim.x) {
        float4 a = acc[i], b = nxt[i];
        a.x = (a.x + b.x) * 0.25f;
        a.y = (a.y + b.y) * 0.25f;
        a.z = (a.z + b.z) * 0.25f;
        a.w = (a.w + b.w) * 0.25f;
        acc[i] = a;
    }
}

extern "C" void kernel_launch(void* const* d_in, const int* in_sizes, int n_in,
                              void* d_out, int out_size, void* d_ws, size_t ws_size,
                              hipStream_t stream) {
    const float* eu   = (const float*)d_in[0];
    const float* ei   = (const float*)d_in[1];
    const int*   erow = (const int*)d_in[2];
    const int*   ecol = (const int*)d_in[3];
    const float* eval = (const float*)d_in[4];

    float* acc = (float*)d_out;

    // workspace layout
    const size_t nodef = (size_t)N_NODES * EMB_DIM;
    char* p = (char*)d_ws;
    float* ws0  = (float*)p; p += nodef * sizeof(float);          // ping
    float* ws1  = (float*)p; p += nodef * sizeof(float);          // pong
    int2*  ev   = (int2*)p;  p += (size_t)N_EDGES * sizeof(int2); // packed (col,val)
    int*   rp   = (int*)p;   p += ((size_t)N_NODES + 1) * sizeof(int);
    int*   cur  = (int*)p;   p += (size_t)N_NODES * sizeof(int);  // counts / cursor
    int*   part = (int*)p;   p += 256 * sizeof(int);              // chunk partials
    const size_t needed = (size_t)(p - (char*)d_ws);

    const int EW_BLOCK = 256;
    const int EW_GRID  = (TOT4 + EW_BLOCK - 1) / EW_BLOCK;        // 75,000
    const int EG       = (N_EDGES + 255) / 256;                   // 11,719
    const int SG       = (N_NODES + 7) / 8;                       // 75,000

    if (ws_size >= needed) {
        // ---- CSR path ----
        k_init<<<EW_GRID, EW_BLOCK, 0, stream>>>(
            (const float4*)eu, (const float4*)ei, (float4*)ws0, (float4*)acc);

        // build CSR (edge list is identical for all 3 layers)
        k_zero_i32<<<1024, 256, 0, stream>>>(cur, N_NODES);
        k_hist<<<EG, 256, 0, stream>>>(erow, cur);
        k_scan_part<<<N_CHUNKS, 256, 0, stream>>>(cur, part);
        k_scan_top<<<1, 1, 0, stream>>>(part, rp);
        k_scan_apply<<<N_CHUNKS, 256, 0, stream>>>(cur, part, rp, cur);
        k_fill<<<EG, 256, 0, stream>>>(erow, ecol, eval, cur, ev);

        // 3 layers, acc fused into the SpMM epilogue
        k_spmm_csr<<<SG, 256, 0, stream>>>(rp, ev, (const float4*)ws0,
                                           (float4*)ws1, (float4*)acc, 0);
        k_spmm_csr<<<SG, 256, 0, stream>>>(rp, ev, (const float4*)ws1,
                                           (float4*)ws0, (float4*)acc, 0);
        k_spmm_csr<<<SG, 256, 0, stream>>>(rp, ev, (const float4*)ws0,
                                           (float4*)ws1, (float4*)acc, 1);
    } else {
        // ---- fallback: previous atomic-scatter path ----
        k_init_old<<<EW_GRID, EW_BLOCK, 0, stream>>>(
            (const float4*)eu, (const float4*)ei,
            (float4*)ws0, (float4*)acc, (float4*)ws1);

        k_spmm_atomic<<<(N_EDGES + 7) / 8, 256, 0, stream>>>(erow, ecol, eval,
                                                             (const float4*)ws0, ws1);
        k_add_zero<<<EW_GRID, EW_BLOCK, 0, stream>>>((float4*)acc, (const float4*)ws1,
                                                     (float4*)ws0);
        k_spmm_atomic<<<(N_EDGES + 7) / 8, 256, 0, stream>>>(erow, ecol, eval,
                                                             (const float4*)ws1, ws0);
        k_add_zero<<<EW_GRID, EW_BLOCK, 0, stream>>>((float4*)acc, (const float4*)ws0,
                                                     (float4*)ws1);
        k_spmm_atomic<<<(N_EDGES + 7) / 8, 256, 0, stream>>>(erow, ecol, eval,
                                                             (const float4*)ws0, ws1);
        k_add_scale<<<EW_GRID, EW_BLOCK, 0, stream>>>((float4*)acc, (const float4*)ws1);
    }
}